// Round 1
// baseline (240.725 us; speedup 1.0000x reference)
//
#include <hip/hip_runtime.h>
#include <hip/hip_bf16.h>

// Problem constants
#define SZ    2048
#define SLEN  128
#define DWE   100
#define DPE   5
#define DEE   100
#define DC    300
#define CIN   210
#define KLOC  10
#define OUTW  1500   // 3*DC + 6*DWE

// GEMM layout constants
#define CINP  224    // padded K per tap (multiple of 32, >= 210)
#define LCOLS 232    // XT row stride in bf16 elems (464 B -> conflict-free-ish b128)
#define LROWS 130    // 128 tokens + 2 zero pad rows
#define CPAD  320    // padded out-channels (20 c-tiles of 16)

typedef short short8 __attribute__((ext_vector_type(8)));
typedef float f32x4 __attribute__((ext_vector_type(4)));

static __device__ __forceinline__ unsigned short f2b(float f) {
  return __builtin_bit_cast(unsigned short, __float2bfloat16(f));
}

// conv_w (300,210,3) fp32  ->  wk[kk][c][i] bf16, zero-padded to [3][320][224]
__global__ void prep_wk(const float* __restrict__ conv_w, unsigned short* __restrict__ wk) {
  int idx = blockIdx.x * 256 + threadIdx.x;
  if (idx >= 3 * CPAD * CINP) return;
  int i  = idx % CINP;
  int c  = (idx / CINP) % CPAD;
  int kk = idx / (CINP * CPAD);
  float v = 0.f;
  if (c < DC && i < CIN) v = conv_w[(c * CIN + i) * 3 + kk];
  wk[idx] = f2b(v);
}

__global__ __launch_bounds__(256, 2) void dmcnn_main(
    const int* __restrict__ inp, const int* __restrict__ pos1, const int* __restrict__ pos2,
    const int* __restrict__ loc, const int* __restrict__ loc_mark, const int* __restrict__ subtype,
    const float* __restrict__ maskL, const float* __restrict__ maskM, const float* __restrict__ maskR,
    const float* __restrict__ word_emb, const float* __restrict__ pos_emb,
    const float* __restrict__ event_emb, const float* __restrict__ conv_b,
    const unsigned short* __restrict__ wk, float* __restrict__ out)
{
  __shared__ unsigned short XT[LROWS * LCOLS];  // 60320 B, XT[t+1][i] = x_i(t), bf16 bits
  __shared__ float evf[DEE];

  const int s   = blockIdx.x;
  const int tid = threadIdx.x;

  // ---- zero LDS image (provides conv zero-pad rows and K-pad cols) ----
  for (int i = tid; i < (LROWS * LCOLS) / 4; i += 256) ((uint2*)XT)[i] = make_uint2(0u, 0u);
  const int stv = subtype[s];
  if (tid < DEE) evf[tid] = (stv == 0) ? 0.f : event_emb[stv * DEE + tid];
  __syncthreads();

  // ---- stage XT: 2 threads per token ----
  {
    const int t = tid >> 1, half = tid & 1;
    unsigned short* row = &XT[(t + 1) * LCOLS];
    const int w = inp[s * SLEN + t];
    if (w != 0) {  // padding_idx=0 -> stays zero
      const float* wp = word_emb + (size_t)w * DWE + half * 50;
      #pragma unroll
      for (int j = 0; j < 25; ++j) {
        float2 v = ((const float2*)wp)[j];
        unsigned u = (unsigned)f2b(v.x) | ((unsigned)f2b(v.y) << 16);
        *(unsigned*)&row[half * 50 + j * 2] = u;
      }
    }
    // positions (no padding_idx on pos_emb)
    const int p = (half == 0 ? pos1 : pos2)[s * SLEN + t];
    const float* pp = pos_emb + p * DPE;
    #pragma unroll
    for (int d = 0; d < DPE; ++d) row[DWE + half * DPE + d] = f2b(pp[d]);
    // event channels (same vector for every token)
    #pragma unroll
    for (int j = 0; j < 25; ++j) {
      float x = evf[half * 50 + j * 2], y = evf[half * 50 + j * 2 + 1];
      unsigned u = (unsigned)f2b(x) | ((unsigned)f2b(y) << 16);
      *(unsigned*)&row[110 + half * 50 + j * 2] = u;
    }
  }
  __syncthreads();

  // ---- GEMM: wave wv owns channels [80wv, 80wv+80), all 128 t ----
  const int wv   = tid >> 6;
  const int lane = tid & 63;
  const int r16  = lane & 15, q16 = lane >> 4;

  f32x4 acc[5][8];
  #pragma unroll
  for (int ci = 0; ci < 5; ++ci)
    #pragma unroll
    for (int tt = 0; tt < 8; ++tt) acc[ci][tt] = (f32x4){0.f, 0.f, 0.f, 0.f};

  const int crow0 = 80 * wv + r16;
  #pragma unroll
  for (int kk = 0; kk < 3; ++kk) {
    for (int kt = 0; kt < 7; ++kt) {
      const int k0 = kt * 32 + q16 * 8;
      short8 a[5];
      #pragma unroll
      for (int ci = 0; ci < 5; ++ci)
        a[ci] = *(const short8*)&wk[(size_t)(kk * CPAD + crow0 + 16 * ci) * CINP + k0];
      #pragma unroll
      for (int tt = 0; tt < 8; ++tt) {
        short8 b = *(const short8*)&XT[(16 * tt + kk + r16) * LCOLS + k0];
        #pragma unroll
        for (int ci = 0; ci < 5; ++ci)
          acc[ci][tt] = __builtin_amdgcn_mfma_f32_16x16x32_bf16(a[ci], b, acc[ci][tt], 0, 0, 0);
      }
    }
  }

  // ---- epilogue: bias + masked max over t (in-register) + tanh + store ----
  float mL[8], mM[8], mR[8];
  #pragma unroll
  for (int tt = 0; tt < 8; ++tt) {
    const int t = 16 * tt + r16;
    mL[tt] = maskL[s * SLEN + t];
    mM[tt] = maskM[s * SLEN + t];
    mR[tt] = maskR[s * SLEN + t];
  }
  float* orow = out + (size_t)s * OUTW;
  #pragma unroll
  for (int ci = 0; ci < 5; ++ci) {
    #pragma unroll
    for (int r = 0; r < 4; ++r) {
      const int c = 80 * wv + 16 * ci + 4 * q16 + r;
      const float bias = (c < DC) ? conv_b[c] : 0.f;
      float vL = -1e30f, vM = -1e30f, vR = -1e30f;
      #pragma unroll
      for (int tt = 0; tt < 8; ++tt) {
        const float v = acc[ci][tt][r] + bias;
        vL = fmaxf(vL, mL[tt] * v);
        vM = fmaxf(vM, mM[tt] * v);
        vR = fmaxf(vR, mR[tt] * v);
      }
      #pragma unroll
      for (int off = 1; off < 16; off <<= 1) {
        vL = fmaxf(vL, __shfl_xor(vL, off));
        vM = fmaxf(vM, __shfl_xor(vM, off));
        vR = fmaxf(vR, __shfl_xor(vR, off));
      }
      if (r16 == 0 && c < DC) {
        orow[c]          = tanhf(vL);
        orow[DC + c]     = tanhf(vM);
        orow[2 * DC + c] = tanhf(vR);
      }
    }
  }

  // ---- loc_embeds: out[s][900..1499], exact fp32 ----
  const int mark = loc_mark[s];
  for (int j = tid; j < 600; j += 256) {
    float v;
    if (j < 400) {
      const int k = j / 100, d = j % 100;
      const int idx = loc[s * KLOC + k];
      v = (idx == 0) ? 0.f : word_emb[(size_t)idx * DWE + d];
    } else if (j < 500) {
      const int d = j - 400;
      float sum = 0.f;
      for (int k = 4; k < 4 + mark; ++k) {
        const int idx = loc[s * KLOC + k];
        sum += (idx == 0) ? 0.f : word_emb[(size_t)idx * DWE + d];
      }
      v = sum / (float)mark;
    } else {
      const int d = j - 500;
      const int idx = loc[s * KLOC + 4 + mark];
      v = (idx == 0) ? 0.f : word_emb[(size_t)idx * DWE + d];
    }
    orow[900 + j] = tanhf(v);
  }
}

extern "C" void kernel_launch(void* const* d_in, const int* in_sizes, int n_in,
                              void* d_out, int out_size, void* d_ws, size_t ws_size,
                              hipStream_t stream) {
  const int*   inp       = (const int*)d_in[0];
  const int*   pos1      = (const int*)d_in[1];
  const int*   pos2      = (const int*)d_in[2];
  const int*   loc       = (const int*)d_in[3];
  const int*   loc_mark  = (const int*)d_in[4];
  const int*   subtype   = (const int*)d_in[5];
  const float* maskL     = (const float*)d_in[6];
  const float* maskM     = (const float*)d_in[7];
  const float* maskR     = (const float*)d_in[8];
  const float* word_emb  = (const float*)d_in[9];
  const float* pos_emb   = (const float*)d_in[10];
  const float* event_emb = (const float*)d_in[11];
  const float* conv_w    = (const float*)d_in[12];
  const float* conv_b    = (const float*)d_in[13];

  unsigned short* wk = (unsigned short*)d_ws;   // 3*320*224 bf16 = 430 KB scratch
  float* out = (float*)d_out;

  prep_wk<<<(3 * CPAD * CINP + 255) / 256, 256, 0, stream>>>(conv_w, wk);
  dmcnn_main<<<SZ, 256, 0, stream>>>(inp, pos1, pos2, loc, loc_mark, subtype,
      maskL, maskM, maskR, word_emb, pos_emb, event_emb, conv_b, wk, out);
}